// Round 3
// baseline (2274.099 us; speedup 1.0000x reference)
//
#include <hip/hip_runtime.h>

// ---------------------------------------------------------------------------
// MPNEncoder (chemprop D-MPNN) forward. MI355X/gfx950.
//   A=100000 atoms, B=200000 bonds, NB=6, H=256, FA=133, FB=147, M=5000, DEPTH=4
//
// Established facts:
//   - inputs fp32, output fp32; ws_size >= 358,432,768 B safe (do not exceed)
//   - sizes[-1] negative: pool uses jnp.repeat drop semantics (round 6 PASS)
//   - split-bf16 MFMA (hi*hi + hi*lo + lo*hi) is numerically free vs fp32
//     (round 7: absmax unchanged at 1.72e10, thr 4.84e10)
//   - round 9: 1923 us. bond = 3x288us at MfmaUtil 18 / VALU 17 / HBM 18 /
//     Occ 38 -> ~65% idle: stall-bound on 13 barrier-synced steps.
//   - round 10 failed on infra ("container failed twice", no pytest output);
//     audit found no OOB/alignment/race/hang — resubmitting same design:
//     (a) bond kernel -> barrier-free fragment-direct form: no LDS, each lane
//         gathers its own MFMA A-fragment (rows are random-gathered anyway,
//         LDS staging bought nothing); waves fully independent.
//     (b) input_bond reuse: ib == initial mb0 (x 2^12). Iters 0,1 skip the
//         FB@Wib phase (38% of MFMA) and add 4096*ib at the epilogue.
//         iter0: mb0->mb1; iter1: mb1->mb0 IN-PLACE (each block touches only
//         its own ib tile; rev-gather reads mb1 -> race-free); iter2
//         recomputes phase-1 (WITH_FB path) since ib is destroyed.
//
// ws layout (total 358,432,768 B, unchanged):
//   [offsets 32 KB][matom fp32 A*256][mb0 B*256 f16][mb1 B*256 f16]
//   [wsplit tail 51.2 MB: persistent pre-split W (2.1 MB used)]
//   end-phase: aggbuf fp32 = mb0; iatom bf16 = mb1[0:51.2MB];
//              t1 bf16 = mb1[51.2:102.4MB]; hid fp32 = mb0 (after cat)
// ---------------------------------------------------------------------------

typedef _Float16 f16;
typedef f16 f16x4 __attribute__((ext_vector_type(4)));
typedef f16 f16x8 __attribute__((ext_vector_type(8)));
typedef __attribute__((ext_vector_type(8))) short bh8;    // 8 bf16 (4 VGPR)
typedef __attribute__((ext_vector_type(4))) float f32x4;  // MFMA C/D

#define MB_SCALE 0.000244140625f  /* 2^-12 */
#define MB_INV   4096.0f          /* 2^12  */
#define AGG_INV  16777216.0f      /* 2^24  */

__device__ __forceinline__ unsigned short f2bf_rne(float f) {
    unsigned u = __float_as_uint(f);
    unsigned r = (u + 0x7fffu + ((u >> 16) & 1u)) >> 16;
    return (unsigned short)r;
}
__device__ __forceinline__ float bfu2f(unsigned short u) {
    return __uint_as_float(((unsigned)u) << 16);
}
__device__ __forceinline__ f32x4 mfma16(bh8 a, bh8 b, f32x4 c) {
    return __builtin_amdgcn_mfma_f32_16x16x32_bf16(a, b, c, 0, 0, 0);
}

// ---------------------------------------------------------------------------
// Pre-split all weights once: transposed [n][k] (k contiguous), bf16 hi/lo.
//   WiaT [256][160] (k pad 133->160) | WibT [256][160] (147->160)
//   WhT  [3][256][256] | WlrT [256][768] | WoT [256][256]
// ---------------------------------------------------------------------------
__global__ __launch_bounds__(256) void wprep_kernel(
    const float* __restrict__ Wia, const float* __restrict__ Wib,
    const float* __restrict__ Wh,  const float* __restrict__ Wlr,
    const float* __restrict__ Wo,  short* __restrict__ ws)
{
    short* WiaT_hi = ws;                 // 40960
    short* WiaT_lo = ws + 40960;
    short* WibT_hi = ws + 81920;         // 40960
    short* WibT_lo = ws + 122880;
    short* WhT_hi  = ws + 163840;        // 196608
    short* WhT_lo  = ws + 360448;
    short* WlrT_hi = ws + 557056;        // 196608
    short* WlrT_lo = ws + 753664;
    short* WoT_hi  = ws + 950272;        // 65536
    short* WoT_lo  = ws + 1015808;       // ends 1081344 shorts = 2.16 MB

    int idx = blockIdx.x * 256 + threadIdx.x;
    float v; short *ph, *pl; int o;
    if (idx < 40960) {
        int n = idx / 160, k = idx - n * 160;
        v = (k < 133) ? Wia[(size_t)k * 256 + n] : 0.f;
        ph = WiaT_hi; pl = WiaT_lo; o = idx;
    } else if (idx < 81920) {
        int j = idx - 40960;
        int n = j / 160, k = j - n * 160;
        v = (k < 147) ? Wib[(size_t)k * 256 + n] : 0.f;
        ph = WibT_hi; pl = WibT_lo; o = j;
    } else if (idx < 278528) {
        int j = idx - 81920;
        int d = j >> 16, rem = j & 65535, n = rem >> 8, k = rem & 255;
        v = Wh[(size_t)d * 65536 + (size_t)k * 256 + n];
        ph = WhT_hi; pl = WhT_lo; o = j;   // layout d*65536 + n*256 + k == j
    } else if (idx < 475136) {
        int j = idx - 278528;
        int n = j / 768, k = j - n * 768;
        v = Wlr[(size_t)k * 256 + n];
        ph = WlrT_hi; pl = WlrT_lo; o = j;
    } else if (idx < 540672) {
        int j = idx - 475136;
        int n = j >> 8, k = j & 255;
        v = Wo[(size_t)k * 256 + n];
        ph = WoT_hi; pl = WoT_lo; o = j;
    } else return;
    unsigned short hb = f2bf_rne(v);
    ph[o] = (short)hb;
    pl[o] = (short)f2bf_rne(v - bfu2f(hb));
}

// ---------------------------------------------------------------------------
// Unified split-bf16 MFMA GEMM (streaming A): 128x256 tile, 512 thr, 8 waves.
// SRC 0: A = fp32 X [M,Kact] (zero-pad to KPAD)       (init GEMMs)
// SRC 1: A = [aggb f32 | matom f32 | iatom bf16], K=768 (cat GEMM)
// SRC 2: A = bf16 X [M,256] (no lo term)              (out GEMM)
// EPI 0: relu->f32  1: relu->bf16  2: relu*MB_SCALE->f16  3: raw->bf16
// EPI 4: relu(x+bias)->f32
// ---------------------------------------------------------------------------
template <int KPAD, int SRC, int EPI>
__global__ __launch_bounds__(512, 4) void mfma_gemm(
    const void* __restrict__ a0, const void* __restrict__ a1,
    const void* __restrict__ a2,
    const short* __restrict__ Bhi, const short* __restrict__ Blo,
    const float* __restrict__ bias, void* __restrict__ outv,
    int M, int Kact)
{
    __shared__ short As_hi[128 * 40];
    __shared__ short As_lo[(SRC == 2) ? 8 : 128 * 40];

    const int tid  = threadIdx.x;
    const int lane = tid & 63;
    const int w    = tid >> 6;          // 0..7
    const int wm   = (w >> 2) * 64;     // {0,64}
    const int wn   = (w & 3) * 64;      // {0,64,128,192}
    const int row0 = blockIdx.x * 128;

    const int sm = tid >> 2;            // staging row 0..127 (4 thr/row)
    const int sk = (tid & 3) * 8;       // staging k-offset 0/8/16/24
    const int fm = lane & 15;
    const int fk = (lane >> 4) * 8;

    int grow = row0 + sm; if (grow > M - 1) grow = M - 1;

    f32x4 acc[4][4];
#pragma unroll
    for (int i = 0; i < 4; ++i)
#pragma unroll
        for (int j = 0; j < 4; ++j) {
            f32x4 z = {0.f, 0.f, 0.f, 0.f};
            acc[i][j] = z;
        }

    for (int k0 = 0; k0 < KPAD; k0 += 32) {
        __syncthreads();
        // ---- stage A tile (pre-split), 8 elems/thread ----
        int base = sm * 40 + sk;
        if (SRC == 0) {
            const float* xrow = (const float*)a0 + (size_t)grow * Kact;
            bh8 h0, l0;
#pragma unroll
            for (int j = 0; j < 8; ++j) {
                int kc = k0 + sk + j;
                float v = (kc < Kact) ? xrow[kc] : 0.f;
                unsigned short hb = f2bf_rne(v);
                h0[j] = (short)hb; l0[j] = (short)f2bf_rne(v - bfu2f(hb));
            }
            *(bh8*)&As_hi[base] = h0;
            *(bh8*)&As_lo[base] = l0;
        } else if (SRC == 1) {
            if (k0 < 512) {
                const float* src = (k0 < 256) ? (const float*)a0 : (const float*)a1;
                int kl = k0 & 255;
                const float4* p = (const float4*)(src + (size_t)grow * 256 + kl + sk);
                float va[8];
#pragma unroll
                for (int q = 0; q < 2; ++q) {
                    float4 f = p[q];
                    va[q * 4 + 0] = f.x; va[q * 4 + 1] = f.y;
                    va[q * 4 + 2] = f.z; va[q * 4 + 3] = f.w;
                }
                bh8 h0, l0;
#pragma unroll
                for (int j = 0; j < 8; ++j) {
                    unsigned short hb = f2bf_rne(va[j]);
                    h0[j] = (short)hb; l0[j] = (short)f2bf_rne(va[j] - bfu2f(hb));
                }
                *(bh8*)&As_hi[base] = h0;
                *(bh8*)&As_lo[base] = l0;
            } else {
                const short* ia = (const short*)a2 + (size_t)grow * 256 + (k0 - 512) + sk;
                bh8 z;
#pragma unroll
                for (int j = 0; j < 8; ++j) z[j] = 0;
                *(bh8*)&As_hi[base] = *(const bh8*)ia;
                *(bh8*)&As_lo[base] = z;
            }
        } else {
            const short* xr = (const short*)a0 + (size_t)grow * 256 + k0 + sk;
            *(bh8*)&As_hi[base] = *(const bh8*)xr;
        }
        __syncthreads();

        // ---- B fragments from pre-split global (L2-resident) ----
        bh8 bhf[4], blf[4];
#pragma unroll
        for (int nt = 0; nt < 4; ++nt) {
            int n = wn + nt * 16 + fm;
            size_t off = (size_t)n * KPAD + k0 + fk;
            bhf[nt] = *(const bh8*)(Bhi + off);
            blf[nt] = *(const bh8*)(Blo + off);
        }
#pragma unroll
        for (int mt = 0; mt < 4; ++mt) {
            int abase = (wm + mt * 16 + fm) * 40 + fk;
            bh8 ah = *(const bh8*)&As_hi[abase];
#pragma unroll
            for (int nt = 0; nt < 4; ++nt) {
                acc[mt][nt] = mfma16(ah, bhf[nt], acc[mt][nt]);
                acc[mt][nt] = mfma16(ah, blf[nt], acc[mt][nt]);
            }
            if (SRC != 2) {
                bh8 al = *(const bh8*)&As_lo[abase];
#pragma unroll
                for (int nt = 0; nt < 4; ++nt)
                    acc[mt][nt] = mfma16(al, bhf[nt], acc[mt][nt]);
            }
        }
    }

    // ---- epilogue (C layout: col=lane&15, row=(lane>>4)*4+r) ----
#pragma unroll
    for (int mt = 0; mt < 4; ++mt) {
        int rbase = row0 + wm + mt * 16 + (lane >> 4) * 4;
#pragma unroll
        for (int nt = 0; nt < 4; ++nt) {
            int col = wn + nt * 16 + fm;
            float bc = (EPI == 4) ? bias[col] : 0.f;
#pragma unroll
            for (int r = 0; r < 4; ++r) {
                int row = rbase + r;
                if (row < M) {
                    size_t o = (size_t)row * 256 + col;
                    float v = acc[mt][nt][r];
                    if (EPI == 0)      ((float*)outv)[o] = fmaxf(v, 0.f);
                    else if (EPI == 1) ((unsigned short*)outv)[o] = f2bf_rne(fmaxf(v, 0.f));
                    else if (EPI == 2) ((f16*)outv)[o] = (f16)(fmaxf(v, 0.f) * MB_SCALE);
                    else if (EPI == 3) ((unsigned short*)outv)[o] = f2bf_rne(v);
                    else               ((float*)outv)[o] = fmaxf(v + bc, 0.f);
                }
            }
        }
    }
}

// ---------------------------------------------------------------------------
// Bond update, fragment-direct, barrier-free, LDS-free:
//   WITH_FB=0: mb_new = relu(4096*ib + (matom[b2a] - 4096*mb_old[b2revb])@Wh) * 2^-12
//   WITH_FB=1: mb_new = relu(relu(FB@Wib) + (...)@Wh) * 2^-12   (recompute ib)
// 256 threads = 4 waves (2 row x 2 col), block tile 128x128, grid (1563, 2).
// Each lane gathers its own A-fragments (row = fm, k-slice = fk) directly
// from global; split in registers; no __syncthreads anywhere.
// ---------------------------------------------------------------------------
template <bool WITH_FB>
__global__ __launch_bounds__(256, 2) void bond_frag_kernel(
    const float* __restrict__ FB,
    const short* __restrict__ WibT_hi, const short* __restrict__ WibT_lo,
    const short* __restrict__ WhT_hi,  const short* __restrict__ WhT_lo,
    const float* __restrict__ matom, const f16* __restrict__ mb_old,
    const f16* __restrict__ ib,
    const int* __restrict__ b2a, const int* __restrict__ b2revb,
    f16* __restrict__ mb_new, int M)
{
    const int tid  = threadIdx.x;
    const int lane = tid & 63;
    const int w    = tid >> 6;          // 0..3
    const int wm   = (w >> 1) * 64;
    const int wn   = (w & 1) * 64;
    const int row0 = blockIdx.x * 128;
    const int colb = blockIdx.y * 128;
    const int fm   = lane & 15;
    const int fk   = (lane >> 4) * 8;

    // gather bases for this lane's 4 A-fragment rows
    const float *ap0, *ap1, *ap2, *ap3;
    const f16 *rp0, *rp1, *rp2, *rp3;
    const float *fp0, *fp1, *fp2, *fp3;
    {
        int r0 = row0 + wm + 0 * 16 + fm; if (r0 > M - 1) r0 = M - 1;
        int r1 = row0 + wm + 1 * 16 + fm; if (r1 > M - 1) r1 = M - 1;
        int r2 = row0 + wm + 2 * 16 + fm; if (r2 > M - 1) r2 = M - 1;
        int r3 = row0 + wm + 3 * 16 + fm; if (r3 > M - 1) r3 = M - 1;
        ap0 = matom + (size_t)b2a[r0] * 256; rp0 = mb_old + (size_t)b2revb[r0] * 256;
        ap1 = matom + (size_t)b2a[r1] * 256; rp1 = mb_old + (size_t)b2revb[r1] * 256;
        ap2 = matom + (size_t)b2a[r2] * 256; rp2 = mb_old + (size_t)b2revb[r2] * 256;
        ap3 = matom + (size_t)b2a[r3] * 256; rp3 = mb_old + (size_t)b2revb[r3] * 256;
        fp0 = FB + (size_t)r0 * 147; fp1 = FB + (size_t)r1 * 147;
        fp2 = FB + (size_t)r2 * 147; fp3 = FB + (size_t)r3 * 147;
    }

    f32x4 acc[4][4];
#pragma unroll
    for (int i = 0; i < 4; ++i)
#pragma unroll
        for (int j = 0; j < 4; ++j) {
            f32x4 z = {0.f, 0.f, 0.f, 0.f};
            acc[i][j] = z;
        }

    if (WITH_FB) {
        // phase 1: input_bond = FB @ Wib (K=147 padded to 160)
        for (int s = 0; s < 5; ++s) {
            int k0 = s * 32;
            bh8 ah[4], al[4];
#pragma unroll
            for (int mt = 0; mt < 4; ++mt) {
                const float* fp = (mt == 0) ? fp0 : (mt == 1) ? fp1 : (mt == 2) ? fp2 : fp3;
#pragma unroll
                for (int j = 0; j < 8; ++j) {
                    int kc = k0 + fk + j;
                    float v = (kc < 147) ? fp[kc] : 0.f;
                    unsigned short hb = f2bf_rne(v);
                    ah[mt][j] = (short)hb;
                    al[mt][j] = (short)f2bf_rne(v - bfu2f(hb));
                }
            }
#pragma unroll
            for (int nt = 0; nt < 4; ++nt) {
                int n = colb + wn + nt * 16 + fm;
                size_t off = (size_t)n * 160 + k0 + fk;
                bh8 bh = *(const bh8*)(WibT_hi + off);
                bh8 bl = *(const bh8*)(WibT_lo + off);
#pragma unroll
                for (int mt = 0; mt < 4; ++mt) {
                    acc[mt][nt] = mfma16(ah[mt], bh, acc[mt][nt]);
                    acc[mt][nt] = mfma16(ah[mt], bl, acc[mt][nt]);
                    acc[mt][nt] = mfma16(al[mt], bh, acc[mt][nt]);
                }
            }
        }
#pragma unroll
        for (int i = 0; i < 4; ++i)
#pragma unroll
            for (int j = 0; j < 4; ++j)
#pragma unroll
                for (int r = 0; r < 4; ++r)
                    acc[i][j][r] = fmaxf(acc[i][j][r], 0.f);
    }

    // phase 2: += (matom[b2a] - 4096*mb_old[b2revb]) @ Wh  (K=256)
#pragma unroll 2
    for (int s = 0; s < 8; ++s) {
        int k0 = s * 32;
        bh8 ah[4], al[4];
#pragma unroll
        for (int mt = 0; mt < 4; ++mt) {
            const float* ap = (mt == 0) ? ap0 : (mt == 1) ? ap1 : (mt == 2) ? ap2 : ap3;
            const f16*   rp = (mt == 0) ? rp0 : (mt == 1) ? rp1 : (mt == 2) ? rp2 : rp3;
            float4 a0 = *(const float4*)(ap + k0 + fk);
            float4 a1 = *(const float4*)(ap + k0 + fk + 4);
            f16x8  rv = *(const f16x8*)(rp + k0 + fk);
            float va[8];
            va[0] = fmaf(-MB_INV, (float)rv[0], a0.x);
            va[1] = fmaf(-MB_INV, (float)rv[1], a0.y);
            va[2] = fmaf(-MB_INV, (float)rv[2], a0.z);
            va[3] = fmaf(-MB_INV, (float)rv[3], a0.w);
            va[4] = fmaf(-MB_INV, (float)rv[4], a1.x);
            va[5] = fmaf(-MB_INV, (float)rv[5], a1.y);
            va[6] = fmaf(-MB_INV, (float)rv[6], a1.z);
            va[7] = fmaf(-MB_INV, (float)rv[7], a1.w);
#pragma unroll
            for (int j = 0; j < 8; ++j) {
                unsigned short hb = f2bf_rne(va[j]);
                ah[mt][j] = (short)hb;
                al[mt][j] = (short)f2bf_rne(va[j] - bfu2f(hb));
            }
        }
#pragma unroll
        for (int nt = 0; nt < 4; ++nt) {
            int n = colb + wn + nt * 16 + fm;
            size_t off = (size_t)n * 256 + k0 + fk;
            bh8 bh = *(const bh8*)(WhT_hi + off);
            bh8 bl = *(const bh8*)(WhT_lo + off);
#pragma unroll
            for (int mt = 0; mt < 4; ++mt) {
                acc[mt][nt] = mfma16(ah[mt], bh, acc[mt][nt]);
                acc[mt][nt] = mfma16(ah[mt], bl, acc[mt][nt]);
                acc[mt][nt] = mfma16(al[mt], bh, acc[mt][nt]);
            }
        }
    }

    // epilogue (C layout: col=lane&15, row=(lane>>4)*4+r); fast path adds ib
#pragma unroll
    for (int mt = 0; mt < 4; ++mt) {
        int rbase = row0 + wm + mt * 16 + (lane >> 4) * 4;
#pragma unroll
        for (int nt = 0; nt < 4; ++nt) {
            int col = colb + wn + nt * 16 + fm;
#pragma unroll
            for (int r = 0; r < 4; ++r) {
                int row = rbase + r;
                if (row < M) {
                    size_t o = (size_t)row * 256 + col;
                    float v = acc[mt][nt][r];
                    if (!WITH_FB) v = fmaf(MB_INV, (float)ib[o], v);
                    mb_new[o] = (f16)(fmaxf(v, 0.f) * MB_SCALE);
                }
            }
        }
    }
}

// agg = sum_j(mb[a2b[a,j]]) * max_j(mb[a2b[a,j]]) per channel, true scale.
// 4 atoms/block, 64 lanes/atom, f16x4 (8B/lane) gather loads.
__global__ __launch_bounds__(256) void agg_kernel(
    const f16* __restrict__ mb, const int* __restrict__ a2b,
    float* __restrict__ matom, float* __restrict__ agg_out, int A)
{
    const int a    = blockIdx.x * 4 + (threadIdx.x >> 6);
    const int lane = threadIdx.x & 63;
    if (a >= A) return;
    const int* nb = a2b + (size_t)a * 6;

    f16x4 v0 = *(const f16x4*)(mb + (size_t)nb[0] * 256 + lane * 4);
    float s0 = (float)v0[0], s1 = (float)v0[1], s2 = (float)v0[2], s3 = (float)v0[3];
    float m0 = s0, m1 = s1, m2 = s2, m3 = s3;
#pragma unroll
    for (int j = 1; j < 6; ++j) {
        f16x4 v = *(const f16x4*)(mb + (size_t)nb[j] * 256 + lane * 4);
        float f0 = (float)v[0], f1 = (float)v[1], f2 = (float)v[2], f3 = (float)v[3];
        s0 += f0; s1 += f1; s2 += f2; s3 += f3;
        m0 = fmaxf(m0, f0); m1 = fmaxf(m1, f1);
        m2 = fmaxf(m2, f2); m3 = fmaxf(m3, f3);
    }
    size_t o = (size_t)a * 256 + lane * 4;
    if (agg_out) {
        float4 g = { AGG_INV * s0 * m0, AGG_INV * s1 * m1,
                     AGG_INV * s2 * m2, AGG_INV * s3 * m3 };
        *(float4*)(agg_out + o) = g;
    } else {
        float4 m = *(const float4*)(matom + o);
        m.x += AGG_INV * s0 * m0; m.y += AGG_INV * s1 * m1;
        m.z += AGG_INV * s2 * m2; m.w += AGG_INV * s3 * m3;
        *(float4*)(matom + o) = m;
    }
}

// Exclusive prefix sum of sizes -> offsets (one block, M=5000). Raw, unclipped.
__global__ __launch_bounds__(256) void scan_kernel(
    const int* __restrict__ sizes, int* __restrict__ offsets, int M)
{
    __shared__ int part[256];
    const int t = threadIdx.x;
    const int chunk = (M + 255) / 256;
    int begin = t * chunk;
    int end = begin + chunk; if (end > M) end = M;
    int s = 0;
    for (int i = begin; i < end && i < M; ++i) s += sizes[i];
    part[t] = s;
    __syncthreads();
    for (int off = 1; off < 256; off <<= 1) {
        int v = (t >= off) ? part[t - off] : 0;
        __syncthreads();
        part[t] += v;
        __syncthreads();
    }
    int run = part[t] - s;
    for (int i = begin; i < end && i < M; ++i) { offsets[i] = run; run += sizes[i]; }
}

// Per-molecule mean pooling with jnp.repeat(total_repeat_length=A) DROP
// semantics (sizes[M-1] may be negative).
__global__ __launch_bounds__(256) void pool_kernel(
    const float* __restrict__ hid, const int* __restrict__ offsets,
    const int* __restrict__ sizes, float* __restrict__ out, int M, int A)
{
    const int m = blockIdx.x;
    const int h = threadIdx.x;
    int e = offsets[m];
    int sz = sizes[m];
    int start = e < A ? e : A;          if (start < 0) start = 0;
    int stop  = e + sz; if (stop > A) stop = A; if (stop < 0) stop = 0;
    float s = 0.f;
    for (int i = start; i < stop; ++i)
        s += hid[(size_t)i * 256 + h];
    out[(size_t)m * 256 + h] = s / (float)sz;
}

extern "C" void kernel_launch(void* const* d_in, const int* in_sizes, int n_in,
                              void* d_out, int out_size, void* d_ws, size_t ws_size,
                              hipStream_t stream)
{
    const float* f_atoms = (const float*)d_in[0];
    const float* f_bonds = (const float*)d_in[1];
    const float* W_ia    = (const float*)d_in[2];
    const float* W_ib    = (const float*)d_in[3];
    const float* W_h     = (const float*)d_in[4];
    const float* W_o     = (const float*)d_in[5];
    const float* b_o     = (const float*)d_in[6];
    const float* W_lr    = (const float*)d_in[7];
    const int*   a2b     = (const int*)d_in[8];
    const int*   b2a     = (const int*)d_in[9];
    const int*   b2revb  = (const int*)d_in[10];
    const int*   sizes   = (const int*)d_in[11];
    float* out = (float*)d_out;   // fp32 [5000,256]

    const int An = 100000, Bn = 200000, Mm = 5000;
    const size_t ABYTES = (size_t)An * 256 * 4;   // 102,400,000
    const size_t BBYTES = (size_t)Bn * 256 * 2;   // 102,400,000 (fp16)

    int*   offsets = (int*)d_ws;                                  // 32 KB
    float* matom   = (float*)((char*)d_ws + 32768);               // fp32 [A,256]
    f16*   mb0     = (f16*)((char*)matom + ABYTES);
    f16*   mb1     = (f16*)((char*)mb0 + BBYTES);
    short* wsplit  = (short*)((char*)mb1 + BBYTES);               // 51.2 MB tail
    // total footprint unchanged: 358,432,768 B (proven safe)

    short* WiaT_hi = wsplit;
    short* WiaT_lo = wsplit + 40960;
    short* WibT_hi = wsplit + 81920;
    short* WibT_lo = wsplit + 122880;
    short* WhT_hi  = wsplit + 163840;
    short* WhT_lo  = wsplit + 360448;
    short* WlrT_hi = wsplit + 557056;
    short* WlrT_lo = wsplit + 753664;
    short* WoT_hi  = wsplit + 950272;
    short* WoT_lo  = wsplit + 1015808;

    dim3 blk(256);
    dim3 blk512(512);
    dim3 gA((An + 127) / 128, 1);    // 782
    dim3 gB((Bn + 127) / 128, 1);    // 1563
    dim3 gF((Bn + 127) / 128, 2);    // 1563 x 2 (bond fragment kernel)

    wprep_kernel<<<2112, blk, 0, stream>>>(W_ia, W_ib, W_h, W_lr, W_o, wsplit);

    // input projections (split-MFMA)
    mfma_gemm<160, 0, 0><<<gA, blk512, 0, stream>>>(
        f_atoms, nullptr, nullptr, WiaT_hi, WiaT_lo, nullptr, matom, An, 133);
    mfma_gemm<160, 0, 2><<<gB, blk512, 0, stream>>>(
        f_bonds, nullptr, nullptr, WibT_hi, WibT_lo, nullptr, mb0, Bn, 147);

    // message passing (3 iterations); ib == initial mb0, reused by iters 0,1
    // d0: agg(mb0); fast(old=mb0, ib=mb0) -> mb1
    agg_kernel<<<(An + 3) / 4, blk, 0, stream>>>(mb0, a2b, matom, (float*)nullptr, An);
    bond_frag_kernel<false><<<gF, blk, 0, stream>>>(
        f_bonds, WibT_hi, WibT_lo, WhT_hi, WhT_lo,
        matom, mb0, mb0, b2a, b2revb, mb1, Bn);
    // d1: agg(mb1); fast(old=mb1, ib=mb0) -> mb0 IN-PLACE over ib (race-free:
    //     each block reads ib only at its own output tile; gather reads mb1)
    agg_kernel<<<(An + 3) / 4, blk, 0, stream>>>(mb1, a2b, matom, (float*)nullptr, An);
    bond_frag_kernel<false><<<gF, blk, 0, stream>>>(
        f_bonds, WibT_hi, WibT_lo, WhT_hi + 65536, WhT_lo + 65536,
        matom, mb1, mb0, b2a, b2revb, mb0, Bn);
    // d2: agg(mb0); slow (recompute FB@Wib; ib destroyed) -> mb1
    agg_kernel<<<(An + 3) / 4, blk, 0, stream>>>(mb0, a2b, matom, (float*)nullptr, An);
    bond_frag_kernel<true><<<gF, blk, 0, stream>>>(
        f_bonds, WibT_hi, WibT_lo, WhT_hi + 131072, WhT_lo + 131072,
        matom, mb0, nullptr, b2a, b2revb, mb1, Bn);
    // final message_bond = mb1 (same as before)

    float* aggbuf = (float*)mb0;                       // fp32 [A,256]
    agg_kernel<<<(An + 3) / 4, blk, 0, stream>>>(mb1, a2b, matom, aggbuf, An);

    // iatom bf16 -> first half of (now dead) mb1; t1 bf16 -> second half
    unsigned short* iatom = (unsigned short*)mb1;
    unsigned short* t1    = (unsigned short*)((char*)mb1 + 51200000);
    mfma_gemm<160, 0, 1><<<gA, blk512, 0, stream>>>(
        f_atoms, nullptr, nullptr, WiaT_hi, WiaT_lo, nullptr, iatom, An, 133);

    mfma_gemm<768, 1, 3><<<gA, blk512, 0, stream>>>(
        aggbuf, matom, iatom, WlrT_hi, WlrT_lo, nullptr, t1, An, 768);

    float* hid = (float*)mb0;                          // aggbuf dead after cat
    mfma_gemm<256, 2, 4><<<gA, blk512, 0, stream>>>(
        t1, nullptr, nullptr, WoT_hi, WoT_lo, b_o, hid, An, 256);

    scan_kernel<<<1, 256, 0, stream>>>(sizes, offsets, Mm);
    pool_kernel<<<Mm, blk, 0, stream>>>(hid, offsets, sizes, out, Mm, An);
}

// Round 4
// 1822.476 us; speedup vs baseline: 1.2478x; 1.2478x over previous
//
#include <hip/hip_runtime.h>

// ---------------------------------------------------------------------------
// MPNEncoder (chemprop D-MPNN) forward. MI355X/gfx950.
//   A=100000 atoms, B=200000 bonds, NB=6, H=256, FA=133, FB=147, M=5000, DEPTH=4
//
// Established facts:
//   - inputs fp32, output fp32; ws_size >= 358,432,768 B safe (do not exceed)
//   - sizes[-1] negative: pool uses jnp.repeat drop semantics (round 6 PASS)
//   - split-bf16 MFMA (hi*hi + hi*lo + lo*hi) numerically free (absmax 1.72e10)
//   - round 9 (r1): 1923 us total; bond (LDS dbuf, 128x256, 512thr) = 288 us,
//     FETCH 255 MB, MfmaUtil 18 / VALU 17 / Occ 38 -> per-k-step stall-bound.
//   - round 11 (r3): fragment-direct bond REGRESSED (465 us, FETCH 440 MB):
//     per-col-wave gather duplication across blocks became real HBM traffic.
//     LDS staging pays for itself on gathered rows. ALSO PROVEN: ib-reuse
//     (input_bond == 4096*mb0; skip FB@Wib on iters 0,1; add 4096*ib at
//     epilogue) is numerically exact (absmax unchanged, PASS).
//   - THIS ROUND: round-1 bond structure + ib-reuse graft.
//     d0 fast: old=mb0, ib=mb0 -> mb1   (8 k-steps instead of 13)
//     d1 fast: old=mb1, ib=mb0 -> mb0 IN-PLACE (own-tile read+write only;
//              __restrict__ dropped on ib/mb_new; race-free)
//     d2 slow: recompute FB@Wib (13 k-steps), mb0 -> mb1
//
// ws layout (total 358,432,768 B, unchanged):
//   [offsets 32 KB][matom fp32 A*256][mb0 B*256 f16][mb1 B*256 f16]
//   [wsplit tail 51.2 MB: persistent pre-split W (2.1 MB used)]
//   end-phase: aggbuf fp32 = mb0; iatom bf16 = mb1[0:51.2MB];
//              t1 bf16 = mb1[51.2:102.4MB]; hid fp32 = mb0 (after cat)
// ---------------------------------------------------------------------------

typedef _Float16 f16;
typedef f16 f16x4 __attribute__((ext_vector_type(4)));
typedef f16 f16x8 __attribute__((ext_vector_type(8)));
typedef __attribute__((ext_vector_type(8))) short bh8;    // 8 bf16 (4 VGPR)
typedef __attribute__((ext_vector_type(4))) float f32x4;  // MFMA C/D

#define MB_SCALE 0.000244140625f  /* 2^-12 */
#define MB_INV   4096.0f          /* 2^12  */
#define AGG_INV  16777216.0f      /* 2^24  */

__device__ __forceinline__ unsigned short f2bf_rne(float f) {
    unsigned u = __float_as_uint(f);
    unsigned r = (u + 0x7fffu + ((u >> 16) & 1u)) >> 16;
    return (unsigned short)r;
}
__device__ __forceinline__ float bfu2f(unsigned short u) {
    return __uint_as_float(((unsigned)u) << 16);
}
__device__ __forceinline__ f32x4 mfma16(bh8 a, bh8 b, f32x4 c) {
    return __builtin_amdgcn_mfma_f32_16x16x32_bf16(a, b, c, 0, 0, 0);
}

// ---------------------------------------------------------------------------
// Pre-split all weights once: transposed [n][k] (k contiguous), bf16 hi/lo.
//   WiaT [256][160] (k pad 133->160) | WibT [256][160] (147->160)
//   WhT  [3][256][256] | WlrT [256][768] | WoT [256][256]
// ---------------------------------------------------------------------------
__global__ __launch_bounds__(256) void wprep_kernel(
    const float* __restrict__ Wia, const float* __restrict__ Wib,
    const float* __restrict__ Wh,  const float* __restrict__ Wlr,
    const float* __restrict__ Wo,  short* __restrict__ ws)
{
    short* WiaT_hi = ws;                 // 40960
    short* WiaT_lo = ws + 40960;
    short* WibT_hi = ws + 81920;         // 40960
    short* WibT_lo = ws + 122880;
    short* WhT_hi  = ws + 163840;        // 196608
    short* WhT_lo  = ws + 360448;
    short* WlrT_hi = ws + 557056;        // 196608
    short* WlrT_lo = ws + 753664;
    short* WoT_hi  = ws + 950272;        // 65536
    short* WoT_lo  = ws + 1015808;       // ends 1081344 shorts = 2.16 MB

    int idx = blockIdx.x * 256 + threadIdx.x;
    float v; short *ph, *pl; int o;
    if (idx < 40960) {
        int n = idx / 160, k = idx - n * 160;
        v = (k < 133) ? Wia[(size_t)k * 256 + n] : 0.f;
        ph = WiaT_hi; pl = WiaT_lo; o = idx;
    } else if (idx < 81920) {
        int j = idx - 40960;
        int n = j / 160, k = j - n * 160;
        v = (k < 147) ? Wib[(size_t)k * 256 + n] : 0.f;
        ph = WibT_hi; pl = WibT_lo; o = j;
    } else if (idx < 278528) {
        int j = idx - 81920;
        int d = j >> 16, rem = j & 65535, n = rem >> 8, k = rem & 255;
        v = Wh[(size_t)d * 65536 + (size_t)k * 256 + n];
        ph = WhT_hi; pl = WhT_lo; o = j;   // layout d*65536 + n*256 + k == j
    } else if (idx < 475136) {
        int j = idx - 278528;
        int n = j / 768, k = j - n * 768;
        v = Wlr[(size_t)k * 256 + n];
        ph = WlrT_hi; pl = WlrT_lo; o = j;
    } else if (idx < 540672) {
        int j = idx - 475136;
        int n = j >> 8, k = j & 255;
        v = Wo[(size_t)k * 256 + n];
        ph = WoT_hi; pl = WoT_lo; o = j;
    } else return;
    unsigned short hb = f2bf_rne(v);
    ph[o] = (short)hb;
    pl[o] = (short)f2bf_rne(v - bfu2f(hb));
}

// ---------------------------------------------------------------------------
// Unified split-bf16 MFMA GEMM (streaming A): 128x256 tile, 512 thr, 8 waves.
// SRC 0: A = fp32 X [M,Kact] (zero-pad to KPAD)       (init GEMMs)
// SRC 1: A = [aggb f32 | matom f32 | iatom bf16], K=768 (cat GEMM)
// SRC 2: A = bf16 X [M,256] (no lo term)              (out GEMM)
// EPI 0: relu->f32  1: relu->bf16  2: relu*MB_SCALE->f16  3: raw->bf16
// EPI 4: relu(x+bias)->f32
// ---------------------------------------------------------------------------
template <int KPAD, int SRC, int EPI>
__global__ __launch_bounds__(512, 4) void mfma_gemm(
    const void* __restrict__ a0, const void* __restrict__ a1,
    const void* __restrict__ a2,
    const short* __restrict__ Bhi, const short* __restrict__ Blo,
    const float* __restrict__ bias, void* __restrict__ outv,
    int M, int Kact)
{
    __shared__ short As_hi[128 * 40];
    __shared__ short As_lo[(SRC == 2) ? 8 : 128 * 40];

    const int tid  = threadIdx.x;
    const int lane = tid & 63;
    const int w    = tid >> 6;          // 0..7
    const int wm   = (w >> 2) * 64;     // {0,64}
    const int wn   = (w & 3) * 64;      // {0,64,128,192}
    const int row0 = blockIdx.x * 128;

    const int sm = tid >> 2;            // staging row 0..127 (4 thr/row)
    const int sk = (tid & 3) * 8;       // staging k-offset 0/8/16/24
    const int fm = lane & 15;
    const int fk = (lane >> 4) * 8;

    int grow = row0 + sm; if (grow > M - 1) grow = M - 1;

    f32x4 acc[4][4];
#pragma unroll
    for (int i = 0; i < 4; ++i)
#pragma unroll
        for (int j = 0; j < 4; ++j) {
            f32x4 z = {0.f, 0.f, 0.f, 0.f};
            acc[i][j] = z;
        }

    for (int k0 = 0; k0 < KPAD; k0 += 32) {
        __syncthreads();
        // ---- stage A tile (pre-split), 8 elems/thread ----
        int base = sm * 40 + sk;
        if (SRC == 0) {
            const float* xrow = (const float*)a0 + (size_t)grow * Kact;
            bh8 h0, l0;
#pragma unroll
            for (int j = 0; j < 8; ++j) {
                int kc = k0 + sk + j;
                float v = (kc < Kact) ? xrow[kc] : 0.f;
                unsigned short hb = f2bf_rne(v);
                h0[j] = (short)hb; l0[j] = (short)f2bf_rne(v - bfu2f(hb));
            }
            *(bh8*)&As_hi[base] = h0;
            *(bh8*)&As_lo[base] = l0;
        } else if (SRC == 1) {
            if (k0 < 512) {
                const float* src = (k0 < 256) ? (const float*)a0 : (const float*)a1;
                int kl = k0 & 255;
                const float4* p = (const float4*)(src + (size_t)grow * 256 + kl + sk);
                float va[8];
#pragma unroll
                for (int q = 0; q < 2; ++q) {
                    float4 f = p[q];
                    va[q * 4 + 0] = f.x; va[q * 4 + 1] = f.y;
                    va[q * 4 + 2] = f.z; va[q * 4 + 3] = f.w;
                }
                bh8 h0, l0;
#pragma unroll
                for (int j = 0; j < 8; ++j) {
                    unsigned short hb = f2bf_rne(va[j]);
                    h0[j] = (short)hb; l0[j] = (short)f2bf_rne(va[j] - bfu2f(hb));
                }
                *(bh8*)&As_hi[base] = h0;
                *(bh8*)&As_lo[base] = l0;
            } else {
                const short* ia = (const short*)a2 + (size_t)grow * 256 + (k0 - 512) + sk;
                bh8 z;
#pragma unroll
                for (int j = 0; j < 8; ++j) z[j] = 0;
                *(bh8*)&As_hi[base] = *(const bh8*)ia;
                *(bh8*)&As_lo[base] = z;
            }
        } else {
            const short* xr = (const short*)a0 + (size_t)grow * 256 + k0 + sk;
            *(bh8*)&As_hi[base] = *(const bh8*)xr;
        }
        __syncthreads();

        // ---- B fragments from pre-split global (L2-resident) ----
        bh8 bhf[4], blf[4];
#pragma unroll
        for (int nt = 0; nt < 4; ++nt) {
            int n = wn + nt * 16 + fm;
            size_t off = (size_t)n * KPAD + k0 + fk;
            bhf[nt] = *(const bh8*)(Bhi + off);
            blf[nt] = *(const bh8*)(Blo + off);
        }
#pragma unroll
        for (int mt = 0; mt < 4; ++mt) {
            int abase = (wm + mt * 16 + fm) * 40 + fk;
            bh8 ah = *(const bh8*)&As_hi[abase];
#pragma unroll
            for (int nt = 0; nt < 4; ++nt) {
                acc[mt][nt] = mfma16(ah, bhf[nt], acc[mt][nt]);
                acc[mt][nt] = mfma16(ah, blf[nt], acc[mt][nt]);
            }
            if (SRC != 2) {
                bh8 al = *(const bh8*)&As_lo[abase];
#pragma unroll
                for (int nt = 0; nt < 4; ++nt)
                    acc[mt][nt] = mfma16(al, bhf[nt], acc[mt][nt]);
            }
        }
    }

    // ---- epilogue (C layout: col=lane&15, row=(lane>>4)*4+r) ----
#pragma unroll
    for (int mt = 0; mt < 4; ++mt) {
        int rbase = row0 + wm + mt * 16 + (lane >> 4) * 4;
#pragma unroll
        for (int nt = 0; nt < 4; ++nt) {
            int col = wn + nt * 16 + fm;
            float bc = (EPI == 4) ? bias[col] : 0.f;
#pragma unroll
            for (int r = 0; r < 4; ++r) {
                int row = rbase + r;
                if (row < M) {
                    size_t o = (size_t)row * 256 + col;
                    float v = acc[mt][nt][r];
                    if (EPI == 0)      ((float*)outv)[o] = fmaxf(v, 0.f);
                    else if (EPI == 1) ((unsigned short*)outv)[o] = f2bf_rne(fmaxf(v, 0.f));
                    else if (EPI == 2) ((f16*)outv)[o] = (f16)(fmaxf(v, 0.f) * MB_SCALE);
                    else if (EPI == 3) ((unsigned short*)outv)[o] = f2bf_rne(v);
                    else               ((float*)outv)[o] = fmaxf(v + bc, 0.f);
                }
            }
        }
    }
}

// ---------------------------------------------------------------------------
// Bond update via split-bf16 MFMA (round-1 288us structure + ib-reuse):
//   WITH_FB=1: mb_new = relu( relu(FB@Wib) + (matom[b2a] - 4096*mb[b2revb])@Wh ) * 2^-12
//   WITH_FB=0: mb_new = relu( 4096*ib     + (matom[b2a] - 4096*mb[b2revb])@Wh ) * 2^-12
// 128x256 tile, 512 threads, dbuf LDS + register prefetch, 1 barrier/step.
// Virtual k-steps: s=0..4 phase1 (K=160, Wib; WITH_FB only), s=5..12 phase2
// (K=256, Wh). Fast path starts at s=5 (8 steps). ib/mb_new may ALIAS (d1
// in-place): no __restrict__ on them; each thread reads ib[o] then writes
// mb_new[o] at the same o only.
// ---------------------------------------------------------------------------
template <bool WITH_FB>
__global__ __launch_bounds__(512, 4) void bond_mfma_kernel(
    const float* __restrict__ FB,
    const short* __restrict__ WibT_hi, const short* __restrict__ WibT_lo,
    const short* __restrict__ WhT_hi,  const short* __restrict__ WhT_lo,
    const float* __restrict__ matom, const f16* __restrict__ mb_old,
    const f16* ib,
    const int* __restrict__ b2a, const int* __restrict__ b2revb,
    f16* mb_new, int M)
{
    __shared__ short As[2][2][128 * 40];   // [buf][hi|lo]

    const int tid  = threadIdx.x;
    const int lane = tid & 63;
    const int w    = tid >> 6;
    const int wm   = (w >> 2) * 64;
    const int wn   = (w & 3) * 64;
    const int row0 = blockIdx.x * 128;

    const int sm = tid >> 2;            // 0..127
    const int sk = (tid & 3) * 8;       // 0/8/16/24

    int grow = row0 + sm; if (grow > M - 1) grow = M - 1;
    const float* frow = FB + (size_t)grow * 147;
    const float* arow = matom + (size_t)b2a[grow] * 256;
    const f16*   rrow = mb_old + (size_t)b2revb[grow] * 256;

    const int fm = lane & 15;
    const int fk = (lane >> 4) * 8;

    f32x4 acc[4][4];
#pragma unroll
    for (int i = 0; i < 4; ++i)
#pragma unroll
        for (int j = 0; j < 4; ++j) {
            f32x4 z = {0.f, 0.f, 0.f, 0.f};
            acc[i][j] = z;
        }

    float va[8];

    auto load = [&](int s) {
        if (s < 5) {                    // phase 1: stream FB row (K=147 pad 160)
            int kb = s * 32 + sk;
#pragma unroll
            for (int j = 0; j < 8; ++j) {
                int kc = kb + j;
                va[j] = (kc < 147) ? frow[kc] : 0.f;
            }
        } else {                        // phase 2: gathered matom - 4096*rev
            int kb = (s - 5) * 32 + sk;
            const float4* ap = (const float4*)(arow + kb);
            const f16x4*  rp = (const f16x4*)(rrow + kb);
#pragma unroll
            for (int q = 0; q < 2; ++q) {
                float4 a = ap[q]; f16x4 r = rp[q];
                va[q * 4 + 0] = fmaf(-MB_INV, (float)r[0], a.x);
                va[q * 4 + 1] = fmaf(-MB_INV, (float)r[1], a.y);
                va[q * 4 + 2] = fmaf(-MB_INV, (float)r[2], a.z);
                va[q * 4 + 3] = fmaf(-MB_INV, (float)r[3], a.w);
            }
        }
    };
    auto store = [&](int buf) {
        bh8 h, l;
#pragma unroll
        for (int j = 0; j < 8; ++j) {
            unsigned short hb = f2bf_rne(va[j]);
            h[j] = (short)hb;
            l[j] = (short)f2bf_rne(va[j] - bfu2f(hb));
        }
        int base = sm * 40 + sk;
        *(bh8*)&As[buf][0][base] = h;
        *(bh8*)&As[buf][1][base] = l;
    };
    auto compute = [&](int buf, int s) {
        const short *Bh, *Bl; int ldb, k0;
        if (s < 5) { Bh = WibT_hi; Bl = WibT_lo; ldb = 160; k0 = s * 32; }
        else       { Bh = WhT_hi;  Bl = WhT_lo;  ldb = 256; k0 = (s - 5) * 32; }
        bh8 bhf[4], blf[4];
#pragma unroll
        for (int nt = 0; nt < 4; ++nt) {
            int n = wn + nt * 16 + fm;
            size_t off = (size_t)n * ldb + k0 + fk;
            bhf[nt] = *(const bh8*)(Bh + off);
            blf[nt] = *(const bh8*)(Bl + off);
        }
#pragma unroll
        for (int mt = 0; mt < 4; ++mt) {
            int abase = (wm + mt * 16 + fm) * 40 + fk;
            bh8 ah = *(const bh8*)&As[buf][0][abase];
            bh8 al = *(const bh8*)&As[buf][1][abase];
#pragma unroll
            for (int nt = 0; nt < 4; ++nt) {
                acc[mt][nt] = mfma16(ah, bhf[nt], acc[mt][nt]);
                acc[mt][nt] = mfma16(ah, blf[nt], acc[mt][nt]);
                acc[mt][nt] = mfma16(al, bhf[nt], acc[mt][nt]);
            }
        }
    };

    const int S0 = WITH_FB ? 0 : 5;

    // prologue: stage first step into buf 0
    load(S0);
    store(0);
    __syncthreads();

    int cur = 0;
    for (int s = S0; s < 13; ++s) {
        if (s < 12) load(s + 1);        // issue gathers; latency hides under MFMA
        compute(cur, s);
        if (WITH_FB && s == 4) {        // relu(input_bond) between phases
#pragma unroll
            for (int i = 0; i < 4; ++i)
#pragma unroll
                for (int j = 0; j < 4; ++j)
#pragma unroll
                    for (int r = 0; r < 4; ++r)
                        acc[i][j][r] = fmaxf(acc[i][j][r], 0.f);
        }
        if (s < 12) store(cur ^ 1);     // write other buffer (no race with readers)
        __syncthreads();                // publish buf[cur^1]; retire reads of buf[cur]
        cur ^= 1;
    }

#pragma unroll
    for (int mt = 0; mt < 4; ++mt) {
        int rbase = row0 + wm + mt * 16 + (lane >> 4) * 4;
#pragma unroll
        for (int nt = 0; nt < 4; ++nt) {
            int col = wn + nt * 16 + fm;
#pragma unroll
            for (int r = 0; r < 4; ++r) {
                int row = rbase + r;
                if (row < M) {
                    size_t o = (size_t)row * 256 + col;
                    float v = acc[mt][nt][r];
                    if (!WITH_FB) v = fmaf(MB_INV, (float)ib[o], v);
                    mb_new[o] = (f16)(fmaxf(v, 0.f) * MB_SCALE);
                }
            }
        }
    }
}

// agg = sum_j(mb[a2b[a,j]]) * max_j(mb[a2b[a,j]]) per channel, true scale.
// 4 atoms/block, 64 lanes/atom, f16x4 (8B/lane) gather loads.
__global__ __launch_bounds__(256) void agg_kernel(
    const f16* __restrict__ mb, const int* __restrict__ a2b,
    float* __restrict__ matom, float* __restrict__ agg_out, int A)
{
    const int a    = blockIdx.x * 4 + (threadIdx.x >> 6);
    const int lane = threadIdx.x & 63;
    if (a >= A) return;
    const int* nb = a2b + (size_t)a * 6;

    f16x4 v0 = *(const f16x4*)(mb + (size_t)nb[0] * 256 + lane * 4);
    float s0 = (float)v0[0], s1 = (float)v0[1], s2 = (float)v0[2], s3 = (float)v0[3];
    float m0 = s0, m1 = s1, m2 = s2, m3 = s3;
#pragma unroll
    for (int j = 1; j < 6; ++j) {
        f16x4 v = *(const f16x4*)(mb + (size_t)nb[j] * 256 + lane * 4);
        float f0 = (float)v[0], f1 = (float)v[1], f2 = (float)v[2], f3 = (float)v[3];
        s0 += f0; s1 += f1; s2 += f2; s3 += f3;
        m0 = fmaxf(m0, f0); m1 = fmaxf(m1, f1);
        m2 = fmaxf(m2, f2); m3 = fmaxf(m3, f3);
    }
    size_t o = (size_t)a * 256 + lane * 4;
    if (agg_out) {
        float4 g = { AGG_INV * s0 * m0, AGG_INV * s1 * m1,
                     AGG_INV * s2 * m2, AGG_INV * s3 * m3 };
        *(float4*)(agg_out + o) = g;
    } else {
        float4 m = *(const float4*)(matom + o);
        m.x += AGG_INV * s0 * m0; m.y += AGG_INV * s1 * m1;
        m.z += AGG_INV * s2 * m2; m.w += AGG_INV * s3 * m3;
        *(float4*)(matom + o) = m;
    }
}

// Exclusive prefix sum of sizes -> offsets (one block, M=5000). Raw, unclipped.
__global__ __launch_bounds__(256) void scan_kernel(
    const int* __restrict__ sizes, int* __restrict__ offsets, int M)
{
    __shared__ int part[256];
    const int t = threadIdx.x;
    const int chunk = (M + 255) / 256;
    int begin = t * chunk;
    int end = begin + chunk; if (end > M) end = M;
    int s = 0;
    for (int i = begin; i < end && i < M; ++i) s += sizes[i];
    part[t] = s;
    __syncthreads();
    for (int off = 1; off < 256; off <<= 1) {
        int v = (t >= off) ? part[t - off] : 0;
        __syncthreads();
        part[t] += v;
        __syncthreads();
    }
    int run = part[t] - s;
    for (int i = begin; i < end && i < M; ++i) { offsets[i] = run; run += sizes[i]; }
}

// Per-molecule mean pooling with jnp.repeat(total_repeat_length=A) DROP
// semantics (sizes[M-1] may be negative).
__global__ __launch_bounds__(256) void pool_kernel(
    const float* __restrict__ hid, const int* __restrict__ offsets,
    const int* __restrict__ sizes, float* __restrict__ out, int M, int A)
{
    const int m = blockIdx.x;
    const int h = threadIdx.x;
    int e = offsets[m];
    int sz = sizes[m];
    int start = e < A ? e : A;          if (start < 0) start = 0;
    int stop  = e + sz; if (stop > A) stop = A; if (stop < 0) stop = 0;
    float s = 0.f;
    for (int i = start; i < stop; ++i)
        s += hid[(size_t)i * 256 + h];
    out[(size_t)m * 256 + h] = s / (float)sz;
}

extern "C" void kernel_launch(void* const* d_in, const int* in_sizes, int n_in,
                              void* d_out, int out_size, void* d_ws, size_t ws_size,
                              hipStream_t stream)
{
    const float* f_atoms = (const float*)d_in[0];
    const float* f_bonds = (const float*)d_in[1];
    const float* W_ia    = (const float*)d_in[2];
    const float* W_ib    = (const float*)d_in[3];
    const float* W_h     = (const float*)d_in[4];
    const float* W_o     = (const float*)d_in[5];
    const float* b_o     = (const float*)d_in[6];
    const float* W_lr    = (const float*)d_in[7];
    const int*   a2b     = (const int*)d_in[8];
    const int*   b2a     = (const int*)d_in[9];
    const int*   b2revb  = (const int*)d_in[10];
    const int*   sizes   = (const int*)d_in[11];
    float* out = (float*)d_out;   // fp32 [5000,256]

    const int An = 100000, Bn = 200000, Mm = 5000;
    const size_t ABYTES = (size_t)An * 256 * 4;   // 102,400,000
    const size_t BBYTES = (size_t)Bn * 256 * 2;   // 102,400,000 (fp16)

    int*   offsets = (int*)d_ws;                                  // 32 KB
    float* matom   = (float*)((char*)d_ws + 32768);               // fp32 [A,256]
    f16*   mb0     = (f16*)((char*)matom + ABYTES);
    f16*   mb1     = (f16*)((char*)mb0 + BBYTES);
    short* wsplit  = (short*)((char*)mb1 + BBYTES);               // 51.2 MB tail
    // total footprint unchanged: 358,432,768 B (proven safe)

    short* WiaT_hi = wsplit;
    short* WiaT_lo = wsplit + 40960;
    short* WibT_hi = wsplit + 81920;
    short* WibT_lo = wsplit + 122880;
    short* WhT_hi  = wsplit + 163840;
    short* WhT_lo  = wsplit + 360448;
    short* WlrT_hi = wsplit + 557056;
    short* WlrT_lo = wsplit + 753664;
    short* WoT_hi  = wsplit + 950272;
    short* WoT_lo  = wsplit + 1015808;

    dim3 blk(256);
    dim3 blk512(512);
    dim3 gA((An + 127) / 128, 1);    // 782
    dim3 gB((Bn + 127) / 128, 1);    // 1563

    wprep_kernel<<<2112, blk, 0, stream>>>(W_ia, W_ib, W_h, W_lr, W_o, wsplit);

    // input projections (split-MFMA)
    mfma_gemm<160, 0, 0><<<gA, blk512, 0, stream>>>(
        f_atoms, nullptr, nullptr, WiaT_hi, WiaT_lo, nullptr, matom, An, 133);
    mfma_gemm<160, 0, 2><<<gB, blk512, 0, stream>>>(
        f_bonds, nullptr, nullptr, WibT_hi, WibT_lo, nullptr, mb0, Bn, 147);

    // message passing (3 iterations); ib == initial mb0, reused by iters 0,1
    // d0: agg(mb0); fast(old=mb0, ib=mb0) -> mb1
    agg_kernel<<<(An + 3) / 4, blk, 0, stream>>>(mb0, a2b, matom, (float*)nullptr, An);
    bond_mfma_kernel<false><<<gB, blk512, 0, stream>>>(
        f_bonds, WibT_hi, WibT_lo, WhT_hi, WhT_lo,
        matom, mb0, mb0, b2a, b2revb, mb1, Bn);
    // d1: agg(mb1); fast(old=mb1, ib=mb0) -> mb0 IN-PLACE over ib (race-free:
    //     each thread reads ib[o] then writes mb_new[o] at the same o; gather
    //     source is mb1)
    agg_kernel<<<(An + 3) / 4, blk, 0, stream>>>(mb1, a2b, matom, (float*)nullptr, An);
    bond_mfma_kernel<false><<<gB, blk512, 0, stream>>>(
        f_bonds, WibT_hi, WibT_lo, WhT_hi + 65536, WhT_lo + 65536,
        matom, mb1, mb0, b2a, b2revb, mb0, Bn);
    // d2: agg(mb0); slow (recompute FB@Wib; ib destroyed) -> mb1
    agg_kernel<<<(An + 3) / 4, blk, 0, stream>>>(mb0, a2b, matom, (float*)nullptr, An);
    bond_mfma_kernel<true><<<gB, blk512, 0, stream>>>(
        f_bonds, WibT_hi, WibT_lo, WhT_hi + 131072, WhT_lo + 131072,
        matom, mb0, nullptr, b2a, b2revb, mb1, Bn);
    // final message_bond = mb1 (same as before)

    float* aggbuf = (float*)mb0;                       // fp32 [A,256]
    agg_kernel<<<(An + 3) / 4, blk, 0, stream>>>(mb1, a2b, matom, aggbuf, An);

    // iatom bf16 -> first half of (now dead) mb1; t1 bf16 -> second half
    unsigned short* iatom = (unsigned short*)mb1;
    unsigned short* t1    = (unsigned short*)((char*)mb1 + 51200000);
    mfma_gemm<160, 0, 1><<<gA, blk512, 0, stream>>>(
        f_atoms, nullptr, nullptr, WiaT_hi, WiaT_lo, nullptr, iatom, An, 133);

    mfma_gemm<768, 1, 3><<<gA, blk512, 0, stream>>>(
        aggbuf, matom, iatom, WlrT_hi, WlrT_lo, nullptr, t1, An, 768);

    float* hid = (float*)mb0;                          // aggbuf dead after cat
    mfma_gemm<256, 2, 4><<<gA, blk512, 0, stream>>>(
        t1, nullptr, nullptr, WoT_hi, WoT_lo, b_o, hid, An, 256);

    scan_kernel<<<1, 256, 0, stream>>>(sizes, offsets, Mm);
    pool_kernel<<<Mm, blk, 0, stream>>>(hid, offsets, sizes, out, Mm, An);
}